// Round 5
// baseline (283.355 us; speedup 1.0000x reference)
//
#include <hip/hip_runtime.h>
#include <hip/hip_fp16.h>
#include <math.h>

#define WAVE 64
#define KPAD 128   // padded K for W^T (zero-filled cols K..127)
#define NW   8     // waves per block (512 threads); 2 mention chains per wave

typedef float        f32x4 __attribute__((ext_vector_type(4)));
typedef unsigned int u32x4 __attribute__((ext_vector_type(4)));

// fp32 convert-and-accumulate of one 16B chunk (8 halves), named accumulators
#define ACC8T(q,s,A0,A1,A2,A3,A4,A5,A6,A7) {                                 \
    const __half2* hh_ = (const __half2*)&(q);                               \
    float2 f0_=__half22float2(hh_[0]), f1_=__half22float2(hh_[1]);           \
    float2 f2_=__half22float2(hh_[2]), f3_=__half22float2(hh_[3]);           \
    A0+=(s)*f0_.x; A1+=(s)*f0_.y; A2+=(s)*f1_.x; A3+=(s)*f1_.y;              \
    A4+=(s)*f2_.x; A5+=(s)*f2_.y; A6+=(s)*f3_.x; A7+=(s)*f3_.y; }

// depth-2 fp16 add tree over 4 token-rows, then one fp32 convert-add
#define TREE4T(qa,qb,qc,qd,A0,A1,A2,A3,A4,A5,A6,A7) {                        \
    const __half2* p0_ = (const __half2*)&(qa);                              \
    const __half2* p1_ = (const __half2*)&(qb);                              \
    const __half2* p2_ = (const __half2*)&(qc);                              \
    const __half2* p3_ = (const __half2*)&(qd);                              \
    __half2 s0_=__hadd2(__hadd2(p0_[0],p1_[0]),__hadd2(p2_[0],p3_[0]));      \
    __half2 s1_=__hadd2(__hadd2(p0_[1],p1_[1]),__hadd2(p2_[1],p3_[1]));      \
    __half2 s2_=__hadd2(__hadd2(p0_[2],p1_[2]),__hadd2(p2_[2],p3_[2]));      \
    __half2 s3_=__hadd2(__hadd2(p0_[3],p1_[3]),__hadd2(p2_[3],p3_[3]));      \
    float2 f0_=__half22float2(s0_), f1_=__half22float2(s1_);                 \
    float2 f2_=__half22float2(s2_), f3_=__half22float2(s3_);                 \
    A0+=f0_.x; A1+=f0_.y; A2+=f1_.x; A3+=f1_.y;                              \
    A4+=f2_.x; A5+=f2_.y; A6+=f3_.x; A7+=f3_.y; }

// 8 tokens (4 pair-loads) of one mention, full wave, no divergence
#define STEP8T(idxv,j0,A0,A1,A2,A3,A4,A5,A6,A7) {                            \
    int r0_=__shfl(idxv,(j0)+hsel),   r1_=__shfl(idxv,(j0)+2+hsel);          \
    int r2_=__shfl(idxv,(j0)+4+hsel), r3_=__shfl(idxv,(j0)+6+hsel);          \
    float4 q0_=we16[(size_t)r0_*32+c], q1_=we16[(size_t)r1_*32+c];           \
    float4 q2_=we16[(size_t)r2_*32+c], q3_=we16[(size_t)r3_*32+c];           \
    TREE4T(q0_,q1_,q2_,q3_,A0,A1,A2,A3,A4,A5,A6,A7); }

// pair tail (odd count via weight 0), fp32 path
#define PTAIL(idxv,jv,nn,A0,A1,A2,A3,A4,A5,A6,A7)                            \
    for (; (jv) < (nn); (jv) += 2) {                                         \
        int srcl_=(jv)+hsel;                                                 \
        int rr_=__shfl(idxv,(srcl_<(nn))?srcl_:((nn)-1));                    \
        float s_=(srcl_<(nn))?1.0f:0.0f;                                     \
        float4 q_=we16[(size_t)rr_*32+c];                                    \
        ACC8T(q_,s_,A0,A1,A2,A3,A4,A5,A6,A7); }

// merge half-waves, mean, selected-score dot + 32-lane reduce
#define FINISHP(A0,A1,A2,A3,A4,A5,A6,A7,t0v,t1v,pvar) {                      \
    A0+=__shfl_xor(A0,32); A1+=__shfl_xor(A1,32);                            \
    A2+=__shfl_xor(A2,32); A3+=__shfl_xor(A3,32);                            \
    A4+=__shfl_xor(A4,32); A5+=__shfl_xor(A5,32);                            \
    A6+=__shfl_xor(A6,32); A7+=__shfl_xor(A7,32);                            \
    float inv_=1.0f/(float)((t1v)-(t0v));                                    \
    A0*=inv_; A1*=inv_; A2*=inv_; A3*=inv_;                                  \
    A4*=inv_; A5*=inv_; A6*=inv_; A7*=inv_;                                  \
    pvar = A0*u0.x+A1*u0.y+A2*u0.z+A3*u0.w                                   \
         + A4*u1.x+A5*u1.y+A6*u1.z+A7*u1.w;                                  \
    for (int off_=16; off_>0; off_>>=1) pvar += __shfl_xor(pvar,off_); }

// online-softmax update of (mx,sum,z0..z7) with score pv / embedding A0..A7
#define ONLUPD(pv,A0,A1,A2,A3,A4,A5,A6,A7) {                                 \
    float nmx_=fmaxf(mx,pv);                                                 \
    float sc_=__expf(mx-nmx_), w_=__expf((pv)-nmx_);                         \
    sum=sum*sc_+w_;                                                          \
    z0=z0*sc_+w_*A0; z1=z1*sc_+w_*A1; z2=z2*sc_+w_*A2; z3=z3*sc_+w_*A3;      \
    z4=z4*sc_+w_*A4; z5=z5*sc_+w_*A5; z6=z6*sc_+w_*A6; z7=z7*sc_+w_*A7;      \
    mx=nmx_; }

// ---------------------------------------------------------------------------
// K1 (prep), grid sections:
//  [0, nArgBlk):       type_idx[b] = argmax_k typeTensor[b*K+k]  (wave/bag)
//  [+, nTrBlk):        WT[d][c] = fp16((c<K) ? W[c][d] : 0)
//  [+, nConvBlk):      weh = fp16(we)  (grid-strided, NT source loads)
// ---------------------------------------------------------------------------
__global__ __launch_bounds__(256) void k_prep(const float* __restrict__ tt,
                                              const float* __restrict__ lw,
                                              const float* __restrict__ we,
                                              int* __restrict__ type_idx,
                                              __half* __restrict__ wt,
                                              __half* __restrict__ weh,
                                              int B, int K, int D, int V,
                                              int nArgBlk, int nTrBlk) {
    int bx = blockIdx.x;
    if (bx < nArgBlk) {
        int wid  = threadIdx.x >> 6;
        int lane = threadIdx.x & 63;
        int b = bx * (blockDim.x >> 6) + wid;
        if (b >= B) return;
        float best = -INFINITY;
        int   bi   = 0x7fffffff;
        for (int k = lane; k < K; k += WAVE) {
            float v = tt[(size_t)b * K + k];
            if (v > best) { best = v; bi = k; }
        }
        for (int off = 32; off > 0; off >>= 1) {
            float ov = __shfl_down(best, off);
            int   oi = __shfl_down(bi, off);
            if (ov > best || (ov == best && oi < bi)) { best = ov; bi = oi; }
        }
        if (lane == 0) type_idx[b] = bi;
    } else if (bx < nArgBlk + nTrBlk) {
        int bid = bx - nArgBlk;
        int base = (bid * 256 + (int)threadIdx.x) * 4;
        int total = D * KPAD;
        for (int i = 0; i < 4; ++i) {
            int e = base + i;
            if (e >= total) break;
            int d = e >> 7;        // / KPAD
            int c = e & (KPAD - 1);
            wt[e] = (c < K) ? __float2half(lw[(size_t)c * D + d]) : __half(0.0f);
        }
    } else {
        int cid = bx - nArgBlk - nTrBlk;
        size_t n8 = ((size_t)V * D) >> 3;                  // groups of 8 floats
        size_t stride = ((size_t)gridDim.x - nArgBlk - nTrBlk) * 256;
        for (size_t i = (size_t)cid * 256 + threadIdx.x; i < n8; i += stride) {
            f32x4 v0 = __builtin_nontemporal_load((const f32x4*)(we + i * 8));
            f32x4 v1 = __builtin_nontemporal_load((const f32x4*)(we + i * 8 + 4));
            __half2 h0 = __float22half2_rn(make_float2(v0.x, v0.y));
            __half2 h1 = __float22half2_rn(make_float2(v0.z, v0.w));
            __half2 h2 = __float22half2_rn(make_float2(v1.x, v1.y));
            __half2 h3 = __float22half2_rn(make_float2(v1.z, v1.w));
            uint4 u;
            u.x = *reinterpret_cast<const unsigned int*>(&h0);
            u.y = *reinterpret_cast<const unsigned int*>(&h1);
            u.z = *reinterpret_cast<const unsigned int*>(&h2);
            u.w = *reinterpret_cast<const unsigned int*>(&h3);
            ((uint4*)weh)[i] = u;              // keep weh cached (gather input)
        }
    }
}

// ---------------------------------------------------------------------------
// K2 (fused): one block (512 thr = 8 waves) per bag. Each wave owns TWO
// adjacent mention chains (mA = m0+2w+16k, mB = mA+1), processed with DUAL
// accumulators, software-interleaved: 16 chains/bag (round-3 tail
// parallelism) with ZERO exec-mask divergence (round-3's half-wave groups
// serialized both halves: 2x issue). All control flow is wave-uniform
// (mention bounds are scalars). mB's start offset == mA's end (one fewer
// dependent load). Pair-token scheme within each mention (lanes 0-31 token
// j, 32-63 token j+1). Online softmax into one shared (mx,sum,z) per wave;
// 8-way LDS merge; fp16 W^T projection (32 dims/wave).
// ---------------------------------------------------------------------------
__global__ __launch_bounds__(512, 8) void k_fused(const int* __restrict__ fs,
                                                  const int* __restrict__ offs,
                                                  const int* __restrict__ scope,
                                                  const int* __restrict__ type_idx,
                                                  const __half* __restrict__ weh,
                                                  const float* __restrict__ lw,
                                                  const __half* __restrict__ wt,
                                                  float* __restrict__ out,
                                                  int B, int M, int T, int D, int K) {
    __shared__ float  s_acc[NW][256];   // per-wave online accumulator
    __shared__ float  s_stats[NW][2];   // per-wave {runmax, runsum}
    __shared__ float  s_be[256];        // merged, normalized bag embedding
    __shared__ float2 s_part[NW][64];   // projection partials per wave

    int b    = blockIdx.x;
    int tid  = threadIdx.x;
    int wid  = tid >> 6;       // 0..7
    int lane = tid & 63;
    int c    = lane & 31;      // 16B-chunk (8 dims) within row
    int hsel = lane >> 5;      // 0: even token of pair, 1: odd token

    int m0 = scope[b];
    int m1 = scope[b + 1];

    // per-bag selected W row (uniform across block; hidden under first gather)
    int r = type_idx[b];
    const float4* wr = (const float4*)(lw + (size_t)r * D);
    float4 u0 = wr[c * 2];
    float4 u1 = wr[c * 2 + 1];

    const float4* we16 = (const float4*)weh;   // 16B = 8 halves; 32 chunks/row

    // online-softmax state (one chain-state per wave, fed by both mentions)
    float mx = -INFINITY, sum = 0.f;
    float z0=0,z1=0,z2=0,z3=0,z4=0,z5=0,z6=0,z7=0;

    for (int mA = m0 + wid * 2; mA < m1; mA += 2 * NW) {
        int mB   = mA + 1;
        bool hasB = (mB < m1);                 // wave-uniform

        int tA0 = offs[mA];
        int tA1 = (mA + 1 < M) ? offs[mA + 1] : T;
        int tB0 = tA1;                          // offs[mB] == tA1 when hasB
        int tB1 = hasB ? ((mB + 1 < M) ? offs[mB + 1] : T) : tA1;

        int nA  = tA1 - tA0;
        int nB  = hasB ? (tB1 - tB0) : 0;
        int nnA = min(nA, WAVE);
        int nnB = min(nB, WAVE);

        int idxA = (lane < nnA) ? fs[tA0 + lane] : 0;
        int idxB = (lane < nnB) ? fs[tB0 + lane] : 0;   // nnB=0 when !hasB

        float aA0=0,aA1=0,aA2=0,aA3=0,aA4=0,aA5=0,aA6=0,aA7=0;
        float aB0=0,aB1=0,aB2=0,aB3=0,aB4=0,aB5=0,aB6=0,aB7=0;

        int jA = 0, jB = 0;
        // interleaved main: 8 independent row-loads in flight per iteration
        for (; jA + 8 <= nnA && jB + 8 <= nnB; jA += 8, jB += 8) {
            STEP8T(idxA, jA, aA0,aA1,aA2,aA3,aA4,aA5,aA6,aA7);
            STEP8T(idxB, jB, aB0,aB1,aB2,aB3,aB4,aB5,aB6,aB7);
        }
        for (; jA + 8 <= nnA; jA += 8)
            STEP8T(idxA, jA, aA0,aA1,aA2,aA3,aA4,aA5,aA6,aA7);
        for (; jB + 8 <= nnB; jB += 8)
            STEP8T(idxB, jB, aB0,aB1,aB2,aB3,aB4,aB5,aB6,aB7);
        PTAIL(idxA, jA, nnA, aA0,aA1,aA2,aA3,aA4,aA5,aA6,aA7);
        PTAIL(idxB, jB, nnB, aB0,aB1,aB2,aB3,aB4,aB5,aB6,aB7);

        // rare: mentions longer than 64 tokens — extra chunks, solo
        for (int base = tA0 + WAVE; base < tA1; base += WAVE) {
            int nn = min(WAVE, tA1 - base);
            int idx2 = (lane < nn) ? fs[base + lane] : 0;
            int j = 0;
            for (; j + 8 <= nn; j += 8)
                STEP8T(idx2, j, aA0,aA1,aA2,aA3,aA4,aA5,aA6,aA7);
            PTAIL(idx2, j, nn, aA0,aA1,aA2,aA3,aA4,aA5,aA6,aA7);
        }
        for (int base = tB0 + WAVE; base < tB1; base += WAVE) {
            int nn = min(WAVE, tB1 - base);
            int idx2 = (lane < nn) ? fs[base + lane] : 0;
            int j = 0;
            for (; j + 8 <= nn; j += 8)
                STEP8T(idx2, j, aB0,aB1,aB2,aB3,aB4,aB5,aB6,aB7);
            PTAIL(idx2, j, nn, aB0,aB1,aB2,aB3,aB4,aB5,aB6,aB7);
        }

        // epilogue: mean + score + online update (A always, B if present)
        float pA;
        FINISHP(aA0,aA1,aA2,aA3,aA4,aA5,aA6,aA7, tA0, tA1, pA);
        ONLUPD(pA, aA0,aA1,aA2,aA3,aA4,aA5,aA6,aA7);
        if (hasB) {
            float pB;
            FINISHP(aB0,aB1,aB2,aB3,aB4,aB5,aB6,aB7, tB0, tB1, pB);
            ONLUPD(pB, aB0,aB1,aB2,aB3,aB4,aB5,aB6,aB7);
        }
    }

    // ---- deposit per-wave state (lanes 0..31 own dims 8c..8c+7) ----
    if (hsel == 0) {
        ((float4*)s_acc[wid])[c * 2]     = make_float4(z0, z1, z2, z3);
        ((float4*)s_acc[wid])[c * 2 + 1] = make_float4(z4, z5, z6, z7);
    }
    if (lane == 0) { s_stats[wid][0] = mx; s_stats[wid][1] = sum; }
    __syncthreads();

    // ---- 8-way online-softmax merge; one dim per thread (tid<256) ----
    if (tid < 256) {
        float Mx = -INFINITY;
        #pragma unroll
        for (int g = 0; g < NW; ++g) Mx = fmaxf(Mx, s_stats[g][0]);
        // empty wave: mx_g = -inf -> e_g = 0 (its sum/acc are 0 anyway);
        // bag is never empty (scope strictly increasing), so Mx > -inf
        float S = 0.f, be = 0.f;
        #pragma unroll
        for (int g = 0; g < NW; ++g) {
            float e = __expf(s_stats[g][0] - Mx);
            S  += s_stats[g][1] * e;
            be += s_acc[g][tid] * e;
        }
        s_be[tid] = be * (1.0f / S);
    }
    __syncthreads();

    // ---- projection via fp16 W^T: wave w covers dims [32w, 32w+32) ----
    const __half2* wt2 = (const __half2*)wt;    // [D][KPAD/2] half2
    const float* bep = s_be + wid * 32;
    float2 o = make_float2(0.f, 0.f);
    int kc = lane;                              // half2 column (2kc, 2kc+1)
    #pragma unroll
    for (int d4 = 0; d4 < 8; ++d4) {
        float4 b4 = ((const float4*)bep)[d4];   // LDS broadcast read
        int d = wid * 32 + (d4 << 2);
        float2 w0 = __half22float2(wt2[(size_t)(d + 0) * (KPAD/2) + kc]);
        float2 w1 = __half22float2(wt2[(size_t)(d + 1) * (KPAD/2) + kc]);
        float2 w2 = __half22float2(wt2[(size_t)(d + 2) * (KPAD/2) + kc]);
        float2 w3 = __half22float2(wt2[(size_t)(d + 3) * (KPAD/2) + kc]);
        o.x += b4.x*w0.x + b4.y*w1.x + b4.z*w2.x + b4.w*w3.x;
        o.y += b4.x*w0.y + b4.y*w1.y + b4.z*w2.y + b4.w*w3.y;
    }
    s_part[wid][kc] = o;
    __syncthreads();

    if (wid == 0) {
        float2 oo = make_float2(0.f, 0.f);
        #pragma unroll
        for (int g = 0; g < NW; ++g) {
            float2 pw = s_part[g][kc];
            oo.x += pw.x; oo.y += pw.y;
        }
        int k0 = kc * 2;
        float* ob = out + (size_t)b * K;
        if (k0 + 1 < K) {
            ((float2*)ob)[kc] = oo;
        } else if (k0 < K) {
            ob[k0] = oo.x;
        }
    }
}

// ---------------------------------------------------------------------------
extern "C" void kernel_launch(void* const* d_in, const int* in_sizes, int n_in,
                              void* d_out, int out_size, void* d_ws, size_t ws_size,
                              hipStream_t stream) {
    const int*   feature_seq = (const int*)d_in[0];
    const int*   offset_seq  = (const int*)d_in[1];
    const int*   scope       = (const int*)d_in[2];
    const float* typeTensor  = (const float*)d_in[3];
    const float* word_emb    = (const float*)d_in[4];
    const float* linear_w    = (const float*)d_in[5];
    float* out = (float*)d_out;

    const int T = in_sizes[0];
    const int M = in_sizes[1];
    const int B = in_sizes[2] - 1;
    const int K = in_sizes[3] / B;       // 100
    const int D = in_sizes[5] / K;       // 256
    const int V = in_sizes[4] / D;       // 100000

    // workspace carve-up
    char* w = (char*)d_ws;
    auto align256 = [](size_t x) { return (x + 255) & ~(size_t)255; };
    int*    type_idx = (int*)w;    w += align256((size_t)B * sizeof(int));
    __half* wt       = (__half*)w; w += align256((size_t)D * KPAD * sizeof(__half));
    __half* weh      = (__half*)w; // V * D halves

    // K1: argmax + WT transpose + table fp32->fp16
    {
        int bagsPerBlock = 256 / WAVE;
        int nArgBlk  = (B + bagsPerBlock - 1) / bagsPerBlock;
        int nTrBlk   = (D * KPAD + 1023) / 1024;
        int nConvBlk = 4096;
        k_prep<<<nArgBlk + nTrBlk + nConvBlk, 256, 0, stream>>>(
            typeTensor, linear_w, word_emb, type_idx, wt, weh,
            B, K, D, V, nArgBlk, nTrBlk);
    }
    // K2: fused mention means + per-bag online softmax + weighted sum + proj
    {
        k_fused<<<B, 512, 0, stream>>>(feature_seq, offset_seq, scope, type_idx,
                                       weh, linear_w, wt, out, B, M, T, D, K);
    }
}

// Round 6
// 241.735 us; speedup vs baseline: 1.1722x; 1.1722x over previous
//
#include <hip/hip_runtime.h>
#include <hip/hip_fp16.h>
#include <math.h>

#define WAVE 64
#define KPAD 128   // padded K for W^T (zero-filled cols K..127)
#define NW   8     // waves per block (512 threads); 2 mention chains per wave

typedef float        f32x4 __attribute__((ext_vector_type(4)));
typedef unsigned int u32x4 __attribute__((ext_vector_type(4)));

// ---------------------------------------------------------------------------
// K1 (prep), grid sections (conversion section DELETED — fp32 direct gather):
//  [0, nArgBlk):       type_idx[b] = argmax_k typeTensor[b*K+k]  (wave/bag)
//  [+, nTrBlk):        WT[d][c] = fp16((c<K) ? W[c][d] : 0)
// ---------------------------------------------------------------------------
__global__ __launch_bounds__(256) void k_prep(const float* __restrict__ tt,
                                              const float* __restrict__ lw,
                                              int* __restrict__ type_idx,
                                              __half* __restrict__ wt,
                                              int B, int K, int D,
                                              int nArgBlk) {
    int bx = blockIdx.x;
    if (bx < nArgBlk) {
        int wid  = threadIdx.x >> 6;
        int lane = threadIdx.x & 63;
        int b = bx * (blockDim.x >> 6) + wid;
        if (b >= B) return;
        float best = -INFINITY;
        int   bi   = 0x7fffffff;
        for (int k = lane; k < K; k += WAVE) {
            float v = tt[(size_t)b * K + k];
            if (v > best) { best = v; bi = k; }
        }
        for (int off = 32; off > 0; off >>= 1) {
            float ov = __shfl_down(best, off);
            int   oi = __shfl_down(bi, off);
            if (ov > best || (ov == best && oi < bi)) { best = ov; bi = oi; }
        }
        if (lane == 0) type_idx[b] = bi;
    } else {
        int bid = bx - nArgBlk;
        int base = (bid * 256 + (int)threadIdx.x) * 4;
        int total = D * KPAD;
        for (int i = 0; i < 4; ++i) {
            int e = base + i;
            if (e >= total) break;
            int d = e >> 7;        // / KPAD
            int c = e & (KPAD - 1);
            wt[e] = (c < K) ? __float2half(lw[(size_t)c * D + d]) : __half(0.0f);
        }
    }
}

// ---------------------------------------------------------------------------
// K2 (fused): one block (512 thr = 8 waves) per bag; each wave owns TWO
// adjacent mention chains (mA, mB = mA+1), giving 16 chains/bag (round-3
// tail parallelism) with ZERO exec-mask divergence (all control flow is
// wave-uniform: mention bounds are scalars).
// fp32 DIRECT gather: one 1KB embedding row per wave load instruction
// (64 lanes x float4); lane owns dims 4*lane..4*lane+3 -> only 4
// accumulators per mention (round-5's spill came from 16+16 accs vs the
// 64-VGPR cap of launch_bounds(512,8); this fits in ~45).
// The fp32->fp16 table conversion kernel is GONE (~26 us of HBM time):
// round-3 counters showed the gather is latency-bound at 3.6 TB/s L2/L3-side,
// far from BW ceilings, so doubling gather bytes is nearly free.
// Online softmax per wave; 8-way LDS merge; fp16 W^T projection.
// ---------------------------------------------------------------------------
__global__ __launch_bounds__(512, 8) void k_fused(const int* __restrict__ fs,
                                                  const int* __restrict__ offs,
                                                  const int* __restrict__ scope,
                                                  const int* __restrict__ type_idx,
                                                  const float* __restrict__ we,
                                                  const float* __restrict__ lw,
                                                  const __half* __restrict__ wt,
                                                  float* __restrict__ out,
                                                  int B, int M, int T, int D, int K) {
    __shared__ float  s_acc[NW][256];   // per-wave online accumulator
    __shared__ float  s_stats[NW][2];   // per-wave {runmax, runsum}
    __shared__ float  s_be[256];        // merged, normalized bag embedding
    __shared__ float2 s_part[NW][64];   // projection partials per wave

    int b    = blockIdx.x;
    int tid  = threadIdx.x;
    int wid  = tid >> 6;       // 0..7
    int lane = tid & 63;

    int m0 = scope[b];
    int m1 = scope[b + 1];

    // per-bag selected W row: lane owns dims 4*lane..4*lane+3
    int r = type_idx[b];
    float4 u = ((const float4*)(lw + (size_t)r * D))[lane];

    const float4* we4 = (const float4*)we;   // 64 float4 per 1KB row

    // online-softmax state (one chain-state per wave, fed by both mentions)
    float mx = -INFINITY, sum = 0.f;
    float z0=0, z1=0, z2=0, z3=0;

    for (int mA = m0 + wid * 2; mA < m1; mA += 2 * NW) {
        int mB   = mA + 1;
        bool hasB = (mB < m1);                 // wave-uniform

        int tA0 = offs[mA];
        int tA1 = (mA + 1 < M) ? offs[mA + 1] : T;
        int tB0 = tA1;                          // offs[mB] == tA1 when hasB
        int tB1 = hasB ? ((mB + 1 < M) ? offs[mB + 1] : T) : tA1;

        int nA = tA1 - tA0;
        int nB = tB1 - tB0;                     // 0 when !hasB

        float aA0=0,aA1=0,aA2=0,aA3=0;
        float aB0=0,aB1=0,aB2=0,aB3=0;

        // chunked (<=64 tokens per chunk), A/B interleaved at 2+2 tokens:
        // 4 independent 1KB row-loads in flight, wave-uniform control flow
        int cA = tA0, cB = tB0;
        while (cA < tA1 || cB < tB1) {
            int nnA = tA1 - cA; nnA = (nnA > 64) ? 64 : nnA; if (nnA < 0) nnA = 0;
            int nnB = tB1 - cB; nnB = (nnB > 64) ? 64 : nnB; if (nnB < 0) nnB = 0;
            int idxA = (lane < nnA) ? fs[cA + lane] : 0;
            int idxB = (lane < nnB) ? fs[cB + lane] : 0;

            int jA = 0, jB = 0;
            for (; jA + 2 <= nnA && jB + 2 <= nnB; jA += 2, jB += 2) {
                int rA0 = __shfl(idxA, jA), rA1 = __shfl(idxA, jA + 1);
                int rB0 = __shfl(idxB, jB), rB1 = __shfl(idxB, jB + 1);
                float4 qA0 = we4[(size_t)rA0 * 64 + lane];
                float4 qA1 = we4[(size_t)rA1 * 64 + lane];
                float4 qB0 = we4[(size_t)rB0 * 64 + lane];
                float4 qB1 = we4[(size_t)rB1 * 64 + lane];
                aA0 += qA0.x + qA1.x; aA1 += qA0.y + qA1.y;
                aA2 += qA0.z + qA1.z; aA3 += qA0.w + qA1.w;
                aB0 += qB0.x + qB1.x; aB1 += qB0.y + qB1.y;
                aB2 += qB0.z + qB1.z; aB3 += qB0.w + qB1.w;
            }
            for (; jA + 2 <= nnA; jA += 2) {
                int rA0 = __shfl(idxA, jA), rA1 = __shfl(idxA, jA + 1);
                float4 qA0 = we4[(size_t)rA0 * 64 + lane];
                float4 qA1 = we4[(size_t)rA1 * 64 + lane];
                aA0 += qA0.x + qA1.x; aA1 += qA0.y + qA1.y;
                aA2 += qA0.z + qA1.z; aA3 += qA0.w + qA1.w;
            }
            for (; jB + 2 <= nnB; jB += 2) {
                int rB0 = __shfl(idxB, jB), rB1 = __shfl(idxB, jB + 1);
                float4 qB0 = we4[(size_t)rB0 * 64 + lane];
                float4 qB1 = we4[(size_t)rB1 * 64 + lane];
                aB0 += qB0.x + qB1.x; aB1 += qB0.y + qB1.y;
                aB2 += qB0.z + qB1.z; aB3 += qB0.w + qB1.w;
            }
            if (jA < nnA) {                      // odd tail A (wave-uniform)
                int rr = __shfl(idxA, jA);
                float4 q = we4[(size_t)rr * 64 + lane];
                aA0 += q.x; aA1 += q.y; aA2 += q.z; aA3 += q.w;
            }
            if (jB < nnB) {                      // odd tail B (wave-uniform)
                int rr = __shfl(idxB, jB);
                float4 q = we4[(size_t)rr * 64 + lane];
                aB0 += q.x; aB1 += q.y; aB2 += q.z; aB3 += q.w;
            }
            cA += nnA; cB += nnB;
        }

        // ---- epilogue A: mean, score (full-wave reduce), online update ----
        {
            float inv = 1.0f / (float)nA;
            aA0 *= inv; aA1 *= inv; aA2 *= inv; aA3 *= inv;
            float p = aA0*u.x + aA1*u.y + aA2*u.z + aA3*u.w;
            for (int off = 32; off > 0; off >>= 1) p += __shfl_xor(p, off);
            float nmx = fmaxf(mx, p);
            float sc  = __expf(mx - nmx);
            float w   = __expf(p - nmx);
            sum = sum * sc + w;
            z0 = z0*sc + w*aA0; z1 = z1*sc + w*aA1;
            z2 = z2*sc + w*aA2; z3 = z3*sc + w*aA3;
            mx = nmx;
        }
        if (hasB) {
            float inv = 1.0f / (float)nB;
            aB0 *= inv; aB1 *= inv; aB2 *= inv; aB3 *= inv;
            float p = aB0*u.x + aB1*u.y + aB2*u.z + aB3*u.w;
            for (int off = 32; off > 0; off >>= 1) p += __shfl_xor(p, off);
            float nmx = fmaxf(mx, p);
            float sc  = __expf(mx - nmx);
            float w   = __expf(p - nmx);
            sum = sum * sc + w;
            z0 = z0*sc + w*aB0; z1 = z1*sc + w*aB1;
            z2 = z2*sc + w*aB2; z3 = z3*sc + w*aB3;
            mx = nmx;
        }
    }

    // ---- deposit per-wave state (lane owns dims 4*lane..4*lane+3) ----
    ((float4*)s_acc[wid])[lane] = make_float4(z0, z1, z2, z3);
    if (lane == 0) { s_stats[wid][0] = mx; s_stats[wid][1] = sum; }
    __syncthreads();

    // ---- 8-way online-softmax merge; one dim per thread (tid<256) ----
    if (tid < 256) {
        float Mx = -INFINITY;
        #pragma unroll
        for (int g = 0; g < NW; ++g) Mx = fmaxf(Mx, s_stats[g][0]);
        // empty wave: mx_g = -inf -> e_g = 0 (its sum/acc are 0 anyway);
        // bag is never empty (scope strictly increasing), so Mx > -inf
        float S = 0.f, be = 0.f;
        #pragma unroll
        for (int g = 0; g < NW; ++g) {
            float e = __expf(s_stats[g][0] - Mx);
            S  += s_stats[g][1] * e;
            be += s_acc[g][tid] * e;
        }
        s_be[tid] = be * (1.0f / S);
    }
    __syncthreads();

    // ---- projection via fp16 W^T: wave w covers dims [32w, 32w+32) ----
    const __half2* wt2 = (const __half2*)wt;    // [D][KPAD/2] half2
    const float* bep = s_be + wid * 32;
    float2 o = make_float2(0.f, 0.f);
    int kc = lane;                              // half2 column (2kc, 2kc+1)
    #pragma unroll
    for (int d4 = 0; d4 < 8; ++d4) {
        float4 b4 = ((const float4*)bep)[d4];   // LDS broadcast read
        int d = wid * 32 + (d4 << 2);
        float2 w0 = __half22float2(wt2[(size_t)(d + 0) * (KPAD/2) + kc]);
        float2 w1 = __half22float2(wt2[(size_t)(d + 1) * (KPAD/2) + kc]);
        float2 w2 = __half22float2(wt2[(size_t)(d + 2) * (KPAD/2) + kc]);
        float2 w3 = __half22float2(wt2[(size_t)(d + 3) * (KPAD/2) + kc]);
        o.x += b4.x*w0.x + b4.y*w1.x + b4.z*w2.x + b4.w*w3.x;
        o.y += b4.x*w0.y + b4.y*w1.y + b4.z*w2.y + b4.w*w3.y;
    }
    s_part[wid][kc] = o;
    __syncthreads();

    if (wid == 0) {
        float2 oo = make_float2(0.f, 0.f);
        #pragma unroll
        for (int g = 0; g < NW; ++g) {
            float2 pw = s_part[g][kc];
            oo.x += pw.x; oo.y += pw.y;
        }
        int k0 = kc * 2;
        float* ob = out + (size_t)b * K;
        if (k0 + 1 < K) {
            ((float2*)ob)[kc] = oo;
        } else if (k0 < K) {
            ob[k0] = oo.x;
        }
    }
}

// ---------------------------------------------------------------------------
extern "C" void kernel_launch(void* const* d_in, const int* in_sizes, int n_in,
                              void* d_out, int out_size, void* d_ws, size_t ws_size,
                              hipStream_t stream) {
    const int*   feature_seq = (const int*)d_in[0];
    const int*   offset_seq  = (const int*)d_in[1];
    const int*   scope       = (const int*)d_in[2];
    const float* typeTensor  = (const float*)d_in[3];
    const float* word_emb    = (const float*)d_in[4];
    const float* linear_w    = (const float*)d_in[5];
    float* out = (float*)d_out;

    const int T = in_sizes[0];
    const int M = in_sizes[1];
    const int B = in_sizes[2] - 1;
    const int K = in_sizes[3] / B;       // 100
    const int D = in_sizes[5] / K;       // 256

    // workspace carve-up (weh is GONE — fp32 direct gather)
    char* w = (char*)d_ws;
    auto align256 = [](size_t x) { return (x + 255) & ~(size_t)255; };
    int*    type_idx = (int*)w;    w += align256((size_t)B * sizeof(int));
    __half* wt       = (__half*)w; // D * KPAD halves

    // K1: argmax + WT transpose (tiny now)
    {
        int bagsPerBlock = 256 / WAVE;
        int nArgBlk = (B + bagsPerBlock - 1) / bagsPerBlock;
        int nTrBlk  = (D * KPAD + 1023) / 1024;
        k_prep<<<nArgBlk + nTrBlk, 256, 0, stream>>>(
            typeTensor, linear_w, type_idx, wt, B, K, D, nArgBlk);
    }
    // K2: fused mention means + per-bag online softmax + weighted sum + proj
    {
        k_fused<<<B, 512, 0, stream>>>(feature_seq, offset_seq, scope, type_idx,
                                       word_emb, linear_w, wt, out, B, M, T, D, K);
    }
}

// Round 7
// 239.285 us; speedup vs baseline: 1.1842x; 1.0102x over previous
//
#include <hip/hip_runtime.h>
#include <hip/hip_fp16.h>
#include <math.h>

#define WAVE 64
#define KPAD 128   // padded K for W^T (zero-filled cols K..127)
#define NW   8     // waves per block (512 threads); 2 mention chains per wave

typedef float        f32x4 __attribute__((ext_vector_type(4)));
typedef unsigned int u32x4 __attribute__((ext_vector_type(4)));

// fp32 convert-and-accumulate of one 16B chunk (8 halves), weighted
#define ACC8T(q,s,A0,A1,A2,A3,A4,A5,A6,A7) {                                 \
    const __half2* hh_ = (const __half2*)&(q);                               \
    float2 f0_=__half22float2(hh_[0]), f1_=__half22float2(hh_[1]);           \
    float2 f2_=__half22float2(hh_[2]), f3_=__half22float2(hh_[3]);           \
    A0+=(s)*f0_.x; A1+=(s)*f0_.y; A2+=(s)*f1_.x; A3+=(s)*f1_.y;              \
    A4+=(s)*f2_.x; A5+=(s)*f2_.y; A6+=(s)*f3_.x; A7+=(s)*f3_.y; }

// depth-1 fp16 pair-add over 2 token-rows, then one fp32 convert-add
#define TREE2T(qa,qb,A0,A1,A2,A3,A4,A5,A6,A7) {                              \
    const __half2* p0_ = (const __half2*)&(qa);                              \
    const __half2* p1_ = (const __half2*)&(qb);                              \
    __half2 s0_=__hadd2(p0_[0],p1_[0]);                                      \
    __half2 s1_=__hadd2(p0_[1],p1_[1]);                                      \
    __half2 s2_=__hadd2(p0_[2],p1_[2]);                                      \
    __half2 s3_=__hadd2(p0_[3],p1_[3]);                                      \
    float2 f0_=__half22float2(s0_), f1_=__half22float2(s1_);                 \
    float2 f2_=__half22float2(s2_), f3_=__half22float2(s3_);                 \
    A0+=f0_.x; A1+=f0_.y; A2+=f1_.x; A3+=f1_.y;                              \
    A4+=f2_.x; A5+=f2_.y; A6+=f3_.x; A7+=f3_.y; }

// pair tail (odd count via weight 0), fp32 path
#define PTAIL(idxv,jv,nn,A0,A1,A2,A3,A4,A5,A6,A7)                            \
    for (; (jv) < (nn); (jv) += 2) {                                         \
        int srcl_=(jv)+hsel;                                                 \
        int rr_=__shfl(idxv,(srcl_<(nn))?srcl_:((nn)-1));                    \
        float s_=(srcl_<(nn))?1.0f:0.0f;                                     \
        float4 q_=we16[(size_t)rr_*32+c];                                    \
        ACC8T(q_,s_,A0,A1,A2,A3,A4,A5,A6,A7); }

// merge half-waves, mean, selected-score dot + 32-lane reduce
#define FINISHP(A0,A1,A2,A3,A4,A5,A6,A7,nv,pvar) {                           \
    A0+=__shfl_xor(A0,32); A1+=__shfl_xor(A1,32);                            \
    A2+=__shfl_xor(A2,32); A3+=__shfl_xor(A3,32);                            \
    A4+=__shfl_xor(A4,32); A5+=__shfl_xor(A5,32);                            \
    A6+=__shfl_xor(A6,32); A7+=__shfl_xor(A7,32);                            \
    float inv_=1.0f/(float)(nv);                                             \
    A0*=inv_; A1*=inv_; A2*=inv_; A3*=inv_;                                  \
    A4*=inv_; A5*=inv_; A6*=inv_; A7*=inv_;                                  \
    pvar = A0*u0.x+A1*u0.y+A2*u0.z+A3*u0.w                                   \
         + A4*u1.x+A5*u1.y+A6*u1.z+A7*u1.w;                                  \
    for (int off_=16; off_>0; off_>>=1) pvar += __shfl_xor(pvar,off_); }

// online-softmax update of (mx,sum,z0..z7) with score pv / embedding A0..A7
#define ONLUPD(pv,A0,A1,A2,A3,A4,A5,A6,A7) {                                 \
    float nmx_=fmaxf(mx,pv);                                                 \
    float sc_=__expf(mx-nmx_), w_=__expf((pv)-nmx_);                         \
    sum=sum*sc_+w_;                                                          \
    z0=z0*sc_+w_*A0; z1=z1*sc_+w_*A1; z2=z2*sc_+w_*A2; z3=z3*sc_+w_*A3;      \
    z4=z4*sc_+w_*A4; z5=z5*sc_+w_*A5; z6=z6*sc_+w_*A6; z7=z7*sc_+w_*A7;      \
    mx=nmx_; }

// ---------------------------------------------------------------------------
// K1 (prep), grid sections:
//  [0, nArgBlk):       type_idx[b] = argmax_k typeTensor[b*K+k]  (wave/bag)
//  [+, nTrBlk):        WT[d][c] = fp16((c<K) ? W[c][d] : 0)
//  [+, nConvBlk):      weh = fp16(we)  (grid-strided, NT source loads)
// The fp16 table is RESTORED: round-6 measured the gather path BW-bound at
// ~4.3 TB/s (time scaled with bytes, 512MB/118us vs 256MB/71us), so halving
// gather bytes buys ~58us for ~26us of conversion.
// ---------------------------------------------------------------------------
__global__ __launch_bounds__(256) void k_prep(const float* __restrict__ tt,
                                              const float* __restrict__ lw,
                                              const float* __restrict__ we,
                                              int* __restrict__ type_idx,
                                              __half* __restrict__ wt,
                                              __half* __restrict__ weh,
                                              int B, int K, int D, int V,
                                              int nArgBlk, int nTrBlk) {
    int bx = blockIdx.x;
    if (bx < nArgBlk) {
        int wid  = threadIdx.x >> 6;
        int lane = threadIdx.x & 63;
        int b = bx * (blockDim.x >> 6) + wid;
        if (b >= B) return;
        float best = -INFINITY;
        int   bi   = 0x7fffffff;
        for (int k = lane; k < K; k += WAVE) {
            float v = tt[(size_t)b * K + k];
            if (v > best) { best = v; bi = k; }
        }
        for (int off = 32; off > 0; off >>= 1) {
            float ov = __shfl_down(best, off);
            int   oi = __shfl_down(bi, off);
            if (ov > best || (ov == best && oi < bi)) { best = ov; bi = oi; }
        }
        if (lane == 0) type_idx[b] = bi;
    } else if (bx < nArgBlk + nTrBlk) {
        int bid = bx - nArgBlk;
        int base = (bid * 256 + (int)threadIdx.x) * 4;
        int total = D * KPAD;
        for (int i = 0; i < 4; ++i) {
            int e = base + i;
            if (e >= total) break;
            int d = e >> 7;        // / KPAD
            int c = e & (KPAD - 1);
            wt[e] = (c < K) ? __float2half(lw[(size_t)c * D + d]) : __half(0.0f);
        }
    } else {
        int cid = bx - nArgBlk - nTrBlk;
        size_t n8 = ((size_t)V * D) >> 3;                  // groups of 8 floats
        size_t stride = ((size_t)gridDim.x - nArgBlk - nTrBlk) * 256;
        for (size_t i = (size_t)cid * 256 + threadIdx.x; i < n8; i += stride) {
            f32x4 v0 = __builtin_nontemporal_load((const f32x4*)(we + i * 8));
            f32x4 v1 = __builtin_nontemporal_load((const f32x4*)(we + i * 8 + 4));
            __half2 h0 = __float22half2_rn(make_float2(v0.x, v0.y));
            __half2 h1 = __float22half2_rn(make_float2(v0.z, v0.w));
            __half2 h2 = __float22half2_rn(make_float2(v1.x, v1.y));
            __half2 h3 = __float22half2_rn(make_float2(v1.z, v1.w));
            uint4 u;
            u.x = *reinterpret_cast<const unsigned int*>(&h0);
            u.y = *reinterpret_cast<const unsigned int*>(&h1);
            u.z = *reinterpret_cast<const unsigned int*>(&h2);
            u.w = *reinterpret_cast<const unsigned int*>(&h3);
            ((uint4*)weh)[i] = u;              // keep weh cached (gather input)
        }
    }
}

// ---------------------------------------------------------------------------
// K2 (fused): one block (512 thr = 8 waves) per bag; each wave owns TWO
// adjacent mention chains (mA, mB = mA+1) -> 16 chains/bag, ZERO exec-mask
// divergence (all control flow wave-uniform; round-6's proven structure).
// fp16 pair-row gather: one wave load = 2 token rows (lanes 0-31 token j,
// 32-63 token j+1, 16B/lane). Per iter each chain loads 2 float4 (4 tokens):
// 4 loads in flight + 16 accumulators ~ 50 VGPR. launch_bounds(512,6)
// (VGPR cap ~85) avoids round-5's forced spill while keeping 3 blocks/CU.
// depth-1 fp16 pair-add then fp32 convert-add (round-3 numerics class).
// Online softmax per wave; 8-way LDS merge; fp16 W^T projection.
// ---------------------------------------------------------------------------
__global__ __launch_bounds__(512, 6) void k_fused(const int* __restrict__ fs,
                                                  const int* __restrict__ offs,
                                                  const int* __restrict__ scope,
                                                  const int* __restrict__ type_idx,
                                                  const __half* __restrict__ weh,
                                                  const float* __restrict__ lw,
                                                  const __half* __restrict__ wt,
                                                  float* __restrict__ out,
                                                  int B, int M, int T, int D, int K) {
    __shared__ float  s_acc[NW][256];   // per-wave online accumulator
    __shared__ float  s_stats[NW][2];   // per-wave {runmax, runsum}
    __shared__ float  s_be[256];        // merged, normalized bag embedding
    __shared__ float2 s_part[NW][64];   // projection partials per wave

    int b    = blockIdx.x;
    int tid  = threadIdx.x;
    int wid  = tid >> 6;       // 0..7
    int lane = tid & 63;
    int c    = lane & 31;      // 16B-chunk (8 dims) within row
    int hsel = lane >> 5;      // 0: even token of pair, 1: odd token

    int m0 = scope[b];
    int m1 = scope[b + 1];

    // per-bag selected W row (uniform across block; hidden under first gather)
    int r = type_idx[b];
    const float4* wr = (const float4*)(lw + (size_t)r * D);
    float4 u0 = wr[c * 2];
    float4 u1 = wr[c * 2 + 1];

    const float4* we16 = (const float4*)weh;   // 16B = 8 halves; 32 chunks/row

    // online-softmax state (one chain-state per wave, fed by both mentions)
    float mx = -INFINITY, sum = 0.f;
    float z0=0,z1=0,z2=0,z3=0,z4=0,z5=0,z6=0,z7=0;

    for (int mA = m0 + wid * 2; mA < m1; mA += 2 * NW) {
        int mB   = mA + 1;
        bool hasB = (mB < m1);                 // wave-uniform

        int tA0 = offs[mA];
        int tA1 = (mA + 1 < M) ? offs[mA + 1] : T;
        int tB0 = tA1;                          // offs[mB] == tA1 when hasB
        int tB1 = hasB ? ((mB + 1 < M) ? offs[mB + 1] : T) : tA1;

        int nA = tA1 - tA0;
        int nB = tB1 - tB0;                     // 0 when !hasB

        float aA0=0,aA1=0,aA2=0,aA3=0,aA4=0,aA5=0,aA6=0,aA7=0;
        float aB0=0,aB1=0,aB2=0,aB3=0,aB4=0,aB5=0,aB6=0,aB7=0;

        // chunked (<=64 tokens per chunk), A/B interleaved at 4+4 tokens:
        // 4 independent 1KB pair-row loads in flight, wave-uniform control
        int cA = tA0, cB = tB0;
        while (cA < tA1 || cB < tB1) {
            int nnA = tA1 - cA; nnA = (nnA > 64) ? 64 : nnA; if (nnA < 0) nnA = 0;
            int nnB = tB1 - cB; nnB = (nnB > 64) ? 64 : nnB; if (nnB < 0) nnB = 0;
            int idxA = (lane < nnA) ? fs[cA + lane] : 0;
            int idxB = (lane < nnB) ? fs[cB + lane] : 0;

            int jA = 0, jB = 0;
            for (; jA + 4 <= nnA && jB + 4 <= nnB; jA += 4, jB += 4) {
                int rA0 = __shfl(idxA, jA + hsel);
                int rA1 = __shfl(idxA, jA + 2 + hsel);
                int rB0 = __shfl(idxB, jB + hsel);
                int rB1 = __shfl(idxB, jB + 2 + hsel);
                float4 qA0 = we16[(size_t)rA0 * 32 + c];
                float4 qA1 = we16[(size_t)rA1 * 32 + c];
                float4 qB0 = we16[(size_t)rB0 * 32 + c];
                float4 qB1 = we16[(size_t)rB1 * 32 + c];
                TREE2T(qA0,qA1, aA0,aA1,aA2,aA3,aA4,aA5,aA6,aA7);
                TREE2T(qB0,qB1, aB0,aB1,aB2,aB3,aB4,aB5,aB6,aB7);
            }
            for (; jA + 4 <= nnA; jA += 4) {
                int rA0 = __shfl(idxA, jA + hsel);
                int rA1 = __shfl(idxA, jA + 2 + hsel);
                float4 qA0 = we16[(size_t)rA0 * 32 + c];
                float4 qA1 = we16[(size_t)rA1 * 32 + c];
                TREE2T(qA0,qA1, aA0,aA1,aA2,aA3,aA4,aA5,aA6,aA7);
            }
            for (; jB + 4 <= nnB; jB += 4) {
                int rB0 = __shfl(idxB, jB + hsel);
                int rB1 = __shfl(idxB, jB + 2 + hsel);
                float4 qB0 = we16[(size_t)rB0 * 32 + c];
                float4 qB1 = we16[(size_t)rB1 * 32 + c];
                TREE2T(qB0,qB1, aB0,aB1,aB2,aB3,aB4,aB5,aB6,aB7);
            }
            PTAIL(idxA, jA, nnA, aA0,aA1,aA2,aA3,aA4,aA5,aA6,aA7);
            PTAIL(idxB, jB, nnB, aB0,aB1,aB2,aB3,aB4,aB5,aB6,aB7);
            cA += nnA; cB += nnB;
        }

        // epilogue: mean + score + online update (A always, B if present)
        float pA;
        FINISHP(aA0,aA1,aA2,aA3,aA4,aA5,aA6,aA7, nA, pA);
        ONLUPD(pA, aA0,aA1,aA2,aA3,aA4,aA5,aA6,aA7);
        if (hasB) {
            float pB;
            FINISHP(aB0,aB1,aB2,aB3,aB4,aB5,aB6,aB7, nB, pB);
            ONLUPD(pB, aB0,aB1,aB2,aB3,aB4,aB5,aB6,aB7);
        }
    }

    // ---- deposit per-wave state (lanes 0..31 own dims 8c..8c+7) ----
    if (hsel == 0) {
        ((float4*)s_acc[wid])[c * 2]     = make_float4(z0, z1, z2, z3);
        ((float4*)s_acc[wid])[c * 2 + 1] = make_float4(z4, z5, z6, z7);
    }
    if (lane == 0) { s_stats[wid][0] = mx; s_stats[wid][1] = sum; }
    __syncthreads();

    // ---- 8-way online-softmax merge; one dim per thread (tid<256) ----
    if (tid < 256) {
        float Mx = -INFINITY;
        #pragma unroll
        for (int g = 0; g < NW; ++g) Mx = fmaxf(Mx, s_stats[g][0]);
        // empty wave: mx_g = -inf -> e_g = 0 (its sum/acc are 0 anyway);
        // bag is never empty (scope strictly increasing), so Mx > -inf
        float S = 0.f, be = 0.f;
        #pragma unroll
        for (int g = 0; g < NW; ++g) {
            float e = __expf(s_stats[g][0] - Mx);
            S  += s_stats[g][1] * e;
            be += s_acc[g][tid] * e;
        }
        s_be[tid] = be * (1.0f / S);
    }
    __syncthreads();

    // ---- projection via fp16 W^T: wave w covers dims [32w, 32w+32) ----
    const __half2* wt2 = (const __half2*)wt;    // [D][KPAD/2] half2
    const float* bep = s_be + wid * 32;
    float2 o = make_float2(0.f, 0.f);
    int kc = lane;                              // half2 column (2kc, 2kc+1)
    #pragma unroll
    for (int d4 = 0; d4 < 8; ++d4) {
        float4 b4 = ((const float4*)bep)[d4];   // LDS broadcast read
        int d = wid * 32 + (d4 << 2);
        float2 w0 = __half22float2(wt2[(size_t)(d + 0) * (KPAD/2) + kc]);
        float2 w1 = __half22float2(wt2[(size_t)(d + 1) * (KPAD/2) + kc]);
        float2 w2 = __half22float2(wt2[(size_t)(d + 2) * (KPAD/2) + kc]);
        float2 w3 = __half22float2(wt2[(size_t)(d + 3) * (KPAD/2) + kc]);
        o.x += b4.x*w0.x + b4.y*w1.x + b4.z*w2.x + b4.w*w3.x;
        o.y += b4.x*w0.y + b4.y*w1.y + b4.z*w2.y + b4.w*w3.y;
    }
    s_part[wid][kc] = o;
    __syncthreads();

    if (wid == 0) {
        float2 oo = make_float2(0.f, 0.f);
        #pragma unroll
        for (int g = 0; g < NW; ++g) {
            float2 pw = s_part[g][kc];
            oo.x += pw.x; oo.y += pw.y;
        }
        int k0 = kc * 2;
        float* ob = out + (size_t)b * K;
        if (k0 + 1 < K) {
            ((float2*)ob)[kc] = oo;
        } else if (k0 < K) {
            ob[k0] = oo.x;
        }
    }
}

// ---------------------------------------------------------------------------
extern "C" void kernel_launch(void* const* d_in, const int* in_sizes, int n_in,
                              void* d_out, int out_size, void* d_ws, size_t ws_size,
                              hipStream_t stream) {
    const int*   feature_seq = (const int*)d_in[0];
    const int*   offset_seq  = (const int*)d_in[1];
    const int*   scope       = (const int*)d_in[2];
    const float* typeTensor  = (const float*)d_in[3];
    const float* word_emb    = (const float*)d_in[4];
    const float* linear_w    = (const float*)d_in[5];
    float* out = (float*)d_out;

    const int T = in_sizes[0];
    const int M = in_sizes[1];
    const int B = in_sizes[2] - 1;
    const int K = in_sizes[3] / B;       // 100
    const int D = in_sizes[5] / K;       // 256
    const int V = in_sizes[4] / D;       // 100000

    // workspace carve-up
    char* w = (char*)d_ws;
    auto align256 = [](size_t x) { return (x + 255) & ~(size_t)255; };
    int*    type_idx = (int*)w;    w += align256((size_t)B * sizeof(int));
    __half* wt       = (__half*)w; w += align256((size_t)D * KPAD * sizeof(__half));
    __half* weh      = (__half*)w; // V * D halves

    // K1: argmax + WT transpose + table fp32->fp16
    {
        int bagsPerBlock = 256 / WAVE;
        int nArgBlk  = (B + bagsPerBlock - 1) / bagsPerBlock;
        int nTrBlk   = (D * KPAD + 1023) / 1024;
        int nConvBlk = 4096;
        k_prep<<<nArgBlk + nTrBlk + nConvBlk, 256, 0, stream>>>(
            typeTensor, linear_w, word_emb, type_idx, wt, weh,
            B, K, D, V, nArgBlk, nTrBlk);
    }
    // K2: fused mention means + per-bag online softmax + weighted sum + proj
    {
        k_fused<<<B, 512, 0, stream>>>(feature_seq, offset_seq, scope, type_idx,
                                       weh, linear_w, wt, out, B, M, T, D, K);
    }
}